// Round 10
// baseline (24382.809 us; speedup 1.0000x reference)
//
#include <hip/hip_runtime.h>

typedef unsigned short u16;
typedef __bf16 bf16x8 __attribute__((ext_vector_type(8)));
typedef float f32x4 __attribute__((ext_vector_type(4)));
typedef unsigned uint32x4 __attribute__((ext_vector_type(4)));

#define EPSC 1e-6f

// ---------- helpers ----------
__device__ __forceinline__ float b2f(u16 x) { return __uint_as_float(((unsigned)x) << 16); }
__device__ __forceinline__ u16 f2b(float f) {
    unsigned u = __float_as_uint(f);
    unsigned r = (u + 0x7fffu + ((u >> 16) & 1u)) >> 16;
    return (u16)r;
}
__device__ __forceinline__ float softplusf(float x) {
    return fmaxf(x, 0.f) + log1pf(__expf(-fabsf(x)));
}

// coherent (cross-XCD) plain load/store: per-instruction sc0|sc1 policy,
// bypassing the per-XCD caches to the IC coherence point. Not atomics.
// RULE: asm-load destinations MUST be statically-indexed (VGPR-resident);
// a scratch-allocated destination is copied before the async load lands.
__device__ __forceinline__ void ld_cv16_issue(uint32x4& d, const void* p) {
    asm volatile("global_load_dwordx4 %0, %1, off sc0 sc1"
                 : "=v"(d) : "v"((unsigned long long)p) : "memory");
}
__device__ __forceinline__ unsigned ld_cv4(const void* p) {
    unsigned d;
    asm volatile("global_load_dword %0, %1, off sc0 sc1\n\ts_waitcnt vmcnt(0)"
                 : "=v"(d) : "v"((unsigned long long)p) : "memory");
    return d;
}
__device__ __forceinline__ void wait_vm0() {
    asm volatile("s_waitcnt vmcnt(0)" ::: "memory");
    __builtin_amdgcn_sched_barrier(0);
}
__device__ __forceinline__ void st_cv16(void* p, uint32x4 v) {
    asm volatile("global_store_dwordx4 %0, %1, off sc0 sc1"
                 :: "v"((unsigned long long)p), "v"(v) : "memory");
}
__device__ __forceinline__ void st_cv4(void* p, unsigned v) {
    asm volatile("global_store_dword %0, %1, off sc0 sc1"
                 :: "v"((unsigned long long)p), "v"(v) : "memory");
}

// ---------- conversion / transpose kernels ----------
__global__ void conv_x4(u16* __restrict__ dst, const float* __restrict__ x) {
    size_t i4 = (size_t)blockIdx.x * 256 + threadIdx.x;
    size_t o = i4 * 4;
    int d = (int)(o & 511);
    int b = (int)((o >> 9) & 255);
    int t = (int)(o >> 17);
    float4 v = *(const float4*)(x + ((size_t)b * 256 + t) * 512 + d);
    unsigned p0 = (unsigned)f2b(v.x) | ((unsigned)f2b(v.y) << 16);
    unsigned p1 = (unsigned)f2b(v.z) | ((unsigned)f2b(v.w) << 16);
    *(uint2*)(dst + o) = make_uint2(p0, p1);
}

__global__ void conv_f32_bf16(u16* __restrict__ dst, const float* __restrict__ src, int n) {
    int i = blockIdx.x * 256 + threadIdx.x;
    if (i < n) dst[i] = f2b(src[i]);
}

__global__ void tr_conv(u16* __restrict__ dst, const float* __restrict__ src,
                        int R, int C, int ld) {
    int idx = blockIdx.x * 256 + threadIdx.x;
    if (idx >= R * C) return;
    int c = idx / R, r = idx % R;
    dst[idx] = f2b(src[(size_t)r * ld + c]);
}

__global__ void init_ctr(unsigned* bar) {
#pragma unroll
    for (int i = 0; i < 4; i++) bar[threadIdx.x + i * 256] = 0u;
}

// ---------- generic 128x128 bf16 MFMA GEMM (phase A/C) ----------
enum { EPI_PARTIAL = 0, EPI_BF16_RELU = 1, EPI_BF16_NONE = 2,
       EPI_F32_RELU = 3, EPI_F32_SP = 4, EPI_F32_SIG = 5 };

template <int EPI>
__global__ __launch_bounds__(256)
void gemm128(const u16* __restrict__ A0, const u16* __restrict__ A1,
             int lda0, int lda1, int kSplit,
             const u16* __restrict__ Wt, int ldw,
             const float* __restrict__ bias,
             u16* __restrict__ Cb, float* __restrict__ Cf,
             int M, int N, int K, int kChunk) {
    __shared__ __align__(16) u16 As[128 * 72];
    __shared__ __align__(16) u16 Bs[128 * 72];
    const int tid = threadIdx.x;
    const int wid = tid >> 6, lane = tid & 63;
    const int wm = wid >> 1, wn = wid & 1;
    const int lr = lane & 15, lk = lane >> 4;
    const int m0 = blockIdx.y * 128, n0 = blockIdx.x * 128;
    const int kBeg = blockIdx.z * kChunk;
    const int rsub = lane >> 3;
    const int csub = (lane & 7) * 8;

    f32x4 acc[4][4];
#pragma unroll
    for (int i = 0; i < 4; i++)
#pragma unroll
        for (int j = 0; j < 4; j++) { f32x4 z = {0.f, 0.f, 0.f, 0.f}; acc[i][j] = z; }

    for (int kt = 0; kt < kChunk; kt += 64) {
        const int k0 = kBeg + kt;
        const u16* Ap; int kk, lda;
        if (k0 < kSplit) { Ap = A0; kk = k0; lda = lda0; }
        else             { Ap = A1; kk = k0 - kSplit; lda = lda1; }
        uint4 ra[4], rb[4];
#pragma unroll
        for (int i = 0; i < 4; i++) {
            const int q = wid * 4 + i;
            const int r = q * 8 + rsub;
            ra[i] = *(const uint4*)(Ap + (size_t)(m0 + r) * lda + kk + csub);
            rb[i] = *(const uint4*)(Wt + (size_t)(n0 + r) * ldw + k0 + csub);
        }
        __syncthreads();
#pragma unroll
        for (int i = 0; i < 4; i++) {
            const int q = wid * 4 + i;
            const int r = q * 8 + rsub;
            *(uint4*)&As[r * 72 + csub] = ra[i];
            *(uint4*)&Bs[r * 72 + csub] = rb[i];
        }
        __syncthreads();
#pragma unroll
        for (int s = 0; s < 2; s++) {
            bf16x8 af[4], bfr[4];
#pragma unroll
            for (int i = 0; i < 4; i++)
                af[i] = *(const bf16x8*)&As[(wm * 64 + i * 16 + lr) * 72 + s * 32 + lk * 8];
#pragma unroll
            for (int j = 0; j < 4; j++)
                bfr[j] = *(const bf16x8*)&Bs[(wn * 64 + j * 16 + lr) * 72 + s * 32 + lk * 8];
#pragma unroll
            for (int i = 0; i < 4; i++)
#pragma unroll
                for (int j = 0; j < 4; j++)
                    acc[i][j] = __builtin_amdgcn_mfma_f32_16x16x32_bf16(af[i], bfr[j], acc[i][j], 0, 0, 0);
        }
    }

    const int rowb = m0 + wm * 64, colb = n0 + wn * 64;
#pragma unroll
    for (int i = 0; i < 4; i++) {
#pragma unroll
        for (int j = 0; j < 4; j++) {
            const int col = colb + j * 16 + lr;
#pragma unroll
            for (int r = 0; r < 4; r++) {
                const int row = rowb + i * 16 + lk * 4 + r;
                float v = acc[i][j][r];
                if (EPI == EPI_PARTIAL) {
                    Cf[(size_t)blockIdx.z * ((size_t)M * N) + (size_t)row * N + col] = v;
                } else {
                    if (bias) v += bias[col];
                    if (EPI == EPI_BF16_RELU || EPI == EPI_F32_RELU) v = fmaxf(v, 0.f);
                    else if (EPI == EPI_F32_SP)  v = softplusf(v);
                    else if (EPI == EPI_F32_SIG) v = 1.f / (1.f + __expf(-v));
                    if (EPI == EPI_BF16_RELU || EPI == EPI_BF16_NONE) Cb[(size_t)row * N + col] = f2b(v);
                    else Cf[(size_t)row * N + col] = v;
                }
            }
        }
    }
}

// ---------- workspace layout (bytes) ----------
static constexpr size_t oPHIXWT  = 0;
static constexpr size_t oWCATT   = 1048576;
static constexpr size_t oEMW2T   = 9437184;
static constexpr size_t oESW2T   = 9699328;
static constexpr size_t oWIHPHIT = 9961472;
static constexpr size_t oWIHZT   = 16252928;
static constexpr size_t oPMW1T   = 17039360;
static constexpr size_t oPMW2T   = 19136512;
static constexpr size_t oPSW1T   = 19398656;
static constexpr size_t oPSW2T   = 21495808;
static constexpr size_t oDMW1T   = 21757952;
static constexpr size_t oDMW2T   = 24117248;
static constexpr size_t oHS      = 25165824;               // [T+1][B][H] bf16
static constexpr size_t oZBF     = 159907840;              // [T][B][Z] bf16
static constexpr size_t oT12     = 176685056;              // [256][2048] bf16
static constexpr size_t oBAR     = 177733632;
static constexpr size_t oKLDT    = 177737728;
static constexpr size_t oNLLT    = 177738752;
static constexpr size_t oPHI     = 177739776;              // [65536][1024] bf16
static constexpr size_t oGIP     = 311957504;              // [65536][3072] bf16
static constexpr size_t WS_NEED  = 714610688;

static constexpr size_t NZ = (size_t)256 * 256 * 128;
static constexpr size_t O_Z  = 3;
static constexpr size_t O_MU = 3 + NZ;
static constexpr size_t O_STD = 3 + 2 * NZ;
static constexpr size_t O_XM = 3 + 3 * NZ;

// ---------- grid barrier (coherent plain ops, slow polls) ----------
__device__ __forceinline__ void gbar(unsigned* bar, unsigned n) {
    asm volatile("s_waitcnt vmcnt(0)" ::: "memory");
    __syncthreads();
    const int bx = blockIdx.x, tid = threadIdx.x;
    if (bx == 0) {
        if (tid > 0)
            while (ld_cv4(bar + tid * 2) < n) __builtin_amdgcn_s_sleep(32);
        __syncthreads();
        if (tid < 8) st_cv4(bar + 512 + tid * 16, n);
        __syncthreads();
    } else {
        if (tid == 0) {
            st_cv4(bar + bx * 2, n);
            while (ld_cv4(bar + 512 + (bx & 7) * 16) < n) __builtin_amdgcn_s_sleep(32);
        }
        __syncthreads();
    }
}

// ---------- persistent sequential-phase kernel ----------
__global__ __launch_bounds__(256, 1)
void vrnn_seq(const float* __restrict__ eps,
              const float* __restrict__ em_b1, const float* __restrict__ es_b1,
              const float* __restrict__ em_b2, const float* __restrict__ es_b2,
              const float* __restrict__ gbih, const float* __restrict__ gbhh,
              char* ws, float* out) {
    // W1 buffers
    __shared__ __align__(16) u16 SA[16 * 72];
    __shared__ __align__(16) u16 SB[128 * 72];
    __shared__ __align__(16) u16 TH16[16 * 136];
    // W23 buffers (S12 and TH time-share POOL)
    __shared__ __align__(16) char POOL[16 * 2056 * 2];
    __shared__ float zmL[16 * 128], zsL[16 * 128];
    __shared__ __align__(16) u16 zL[16 * 136];

    const int bx = blockIdx.x, tid = threadIdx.x;
    const int wid = tid >> 6, lane = tid & 63;
    const int lr = lane & 15, lk = lane >> 4;

    const u16* wcatT = (const u16*)(ws + oWCATT);
    const u16* emW2T = (const u16*)(ws + oEMW2T);
    const u16* esW2T = (const u16*)(ws + oESW2T);
    const u16* wihZT = (const u16*)(ws + oWIHZT);
    const u16* PHI   = (const u16*)(ws + oPHI);
    const u16* GIP   = (const u16*)(ws + oGIP);
    u16* HS   = (u16*)(ws + oHS);
    u16* ZBFg = (u16*)(ws + oZBF);
    u16* T12g = (u16*)(ws + oT12);
    unsigned* bar = (unsigned*)(ws + oBAR);

    float* outZ  = out + O_Z;
    float* outMu = out + O_MU;
    float* outSd = out + O_STD;

    unsigned nb = 0;
    // W1 tile map (16x128 tiles): XCD xq gets 2 wcat slabs (1 MB, L2-resident)
    const int xq = bx & 7, jq = bx >> 3;
    const int mI = jq >> 1;                // 0..15
    const int nI = xq * 2 + (jq & 1);      // 0..15

    // per-thread W1 A-layout: row (0..15), 16B chunk col
    const int a_row = tid >> 4, a_c8 = (tid & 15) * 8;
    const int a_half = (tid >> 3) & 1;     // which 64-col half this thread's chunk is in
    const int a_lc = (tid & 7) * 8;        // local col within the 64-half
    const int brow = tid >> 1, bkc = (tid & 1) * 32;   // W1 B staging

    u16* S12 = (u16*)POOL;                 // [16][2056]
    u16* TH  = (u16*)POOL;                 // [16][1032] (after S12 dead)

#pragma unroll 1
    for (int t = 0; t < 256; t++) {
        // ======== window 1: T12 = [h_t | phi_t] @ wcat  (256 blocks, 16x128 tiles) ========
        {
            const u16* HSt  = HS  + (size_t)t * 262144 + (size_t)(mI * 16) * 1024;
            const u16* PHIt = PHI + (size_t)t * 262144 + (size_t)(mI * 16) * 1024;
            const u16* Bb   = wcatT + (size_t)(nI * 128) * 2048;

            // A preload: h half PLAIN cached (write-once/read-once addresses are
            // never stale: producer used sc1 write-through, so no dirty copies
            // exist and this address was never cached before). phi plain too.
            uint32x4 ahx[8], apx[8];
#pragma unroll
            for (int p = 0; p < 8; p++)
                ahx[p] = *(const uint32x4*)(HSt + (size_t)a_row * 1024 + a_c8 + p * 128);
#pragma unroll
            for (int p = 0; p < 8; p++)
                apx[p] = *(const uint32x4*)(PHIt + (size_t)a_row * 1024 + a_c8 + p * 128);
            // B ring prologue (depth 2)
            uint32x4 rbr[2][4];
#pragma unroll
            for (int d = 0; d < 2; d++)
#pragma unroll
                for (int j = 0; j < 4; j++)
                    rbr[d][j] = *(const uint32x4*)(Bb + (size_t)brow * 2048 + d * 64 + bkc + j * 8);

            f32x4 acc0 = {0.f,0.f,0.f,0.f}, acc1 = {0.f,0.f,0.f,0.f};
            // FULL unroll: all ahx/apx/rbr indices compile-time -> VGPR-resident
#pragma unroll
            for (int kt = 0; kt < 32; kt++) {
                __syncthreads();
                // stage A (half the threads own this 64-col slice)
                if (a_half == (kt & 1)) {
                    const int p = (kt < 16) ? (kt >> 1) : ((kt - 16) >> 1);
                    *(uint32x4*)&SA[a_row * 72 + a_lc] = (kt < 16) ? ahx[p] : apx[p];
                }
                // stage B
#pragma unroll
                for (int j = 0; j < 4; j++)
                    *(uint32x4*)&SB[brow * 72 + bkc + j * 8] = rbr[kt & 1][j];
                __syncthreads();
                if (kt + 2 < 32) {
#pragma unroll
                    for (int j = 0; j < 4; j++)
                        rbr[kt & 1][j] = *(const uint32x4*)(Bb + (size_t)brow * 2048 + (kt + 2) * 64 + bkc + j * 8);
                }
#pragma unroll
                for (int s = 0; s < 2; s++) {
                    bf16x8 af = *(const bf16x8*)&SA[lr * 72 + s * 32 + lk * 8];
                    bf16x8 b0 = *(const bf16x8*)&SB[(wid * 32 + lr) * 72 + s * 32 + lk * 8];
                    bf16x8 b1 = *(const bf16x8*)&SB[(wid * 32 + 16 + lr) * 72 + s * 32 + lk * 8];
                    acc0 = __builtin_amdgcn_mfma_f32_16x16x32_bf16(af, b0, acc0, 0, 0, 0);
                    acc1 = __builtin_amdgcn_mfma_f32_16x16x32_bf16(af, b1, acc1, 0, 0, 0);
                }
            }
            // epilogue: bias+relu -> LDS repack -> coherent 16B stores
            __syncthreads();
#pragma unroll
            for (int ct = 0; ct < 2; ct++) {
                const int colg = nI * 128 + wid * 32 + ct * 16 + lr;
                const float bb = (colg < 1024) ? em_b1[colg] : es_b1[colg - 1024];
                const f32x4 a = ct ? acc1 : acc0;
#pragma unroll
                for (int r = 0; r < 4; r++)
                    TH16[(lk * 4 + r) * 136 + wid * 32 + ct * 16 + lr] = f2b(fmaxf(a[r] + bb, 0.f));
            }
            __syncthreads();
            st_cv16(T12g + (size_t)(mI * 16 + a_row) * 2048 + nI * 128 + a_c8,
                    *(const uint32x4*)&TH16[a_row * 136 + a_c8]);
        }
        gbar(bar, ++nb);

        // ======== window 2+3 fused: zm/zs -> z -> GRU -> h_{t+1}  (blocks 0..15) ========
        if (bx < 16) {
            const int r0 = bx * 16;
            // T12 rows -> LDS: sc1 loads (T12g address reused every step -> must
            // bypass). 2 static batches of 8; each consumed after its own wait.
            {
                uint32x4 s12r[16];
#pragma unroll
                for (int i = 0; i < 8; i++)
                    ld_cv16_issue(s12r[i], T12g + (size_t)(r0 + i) * 2048 + tid * 8);
                wait_vm0();
#pragma unroll
                for (int i = 8; i < 16; i++)
                    ld_cv16_issue(s12r[i], T12g + (size_t)(r0 + i) * 2048 + tid * 8);
#pragma unroll
                for (int i = 0; i < 8; i++)
                    *(uint32x4*)&S12[i * 2056 + tid * 8] = s12r[i];
                wait_vm0();
#pragma unroll
                for (int i = 8; i < 16; i++)
                    *(uint32x4*)&S12[i * 2056 + tid * 8] = s12r[i];
            }
            __syncthreads();

            // zm/zs: wave pair (wid>>1) -> em or es half; 4 col-tiles per wave
            {
                const int halfz = wid >> 1;
                const u16* Wz = halfz ? esW2T : emW2T;
                f32x4 az[4];
#pragma unroll
                for (int q = 0; q < 4; q++) { f32x4 z = {0.f,0.f,0.f,0.f}; az[q] = z; }
#pragma unroll 4
                for (int ks = 0; ks < 32; ks++) {
                    bf16x8 af = *(const bf16x8*)&S12[lr * 2056 + halfz * 1024 + ks * 32 + lk * 8];
#pragma unroll
                    for (int q = 0; q < 4; q++) {
                        const int c0 = (wid & 1) * 64 + q * 16;
                        bf16x8 bf = *(const bf16x8*)(Wz + (size_t)(c0 + lr) * 1024 + ks * 32 + lk * 8);
                        az[q] = __builtin_amdgcn_mfma_f32_16x16x32_bf16(af, bf, az[q], 0, 0, 0);
                    }
                }
#pragma unroll
                for (int q = 0; q < 4; q++) {
                    const int c = (wid & 1) * 64 + q * 16 + lr;
#pragma unroll
                    for (int r = 0; r < 4; r++) {
                        const int row = lk * 4 + r;
                        if (!halfz) zmL[row * 128 + c] = fmaxf(az[q][r] + em_b2[c], 0.f);
                        else        zsL[row * 128 + c] = softplusf(az[q][r] + es_b2[c]);
                    }
                }
            }
            __syncthreads();

            // z = zm + zs*eps; outputs (plain scalar stores: out+3 not 16B-aligned)
            {
                const int e = tid * 8, row = e >> 7, col = e & 127;
                const size_t o = (size_t)t * 32768 + (size_t)(r0 + row) * 128 + col;
                const float* ep = eps + o;
                float4 e0 = *(const float4*)ep, e1 = *(const float4*)(ep + 4);
                float zmv[8], zsv[8], zv[8];
#pragma unroll
                for (int i = 0; i < 8; i++) {
                    zmv[i] = zmL[row * 128 + col + i];
                    zsv[i] = zsL[row * 128 + col + i];
                    const float ev = (i < 4) ? (&e0.x)[i] : (&e1.x)[i - 4];
                    zv[i] = zmv[i] + zsv[i] * ev;
                }
#pragma unroll
                for (int i = 0; i < 8; i++) {
                    outMu[o + i] = zmv[i];
                    outSd[o + i] = zsv[i];
                    outZ[o + i]  = zv[i];
                }
                uint32x4 zp;
#pragma unroll
                for (int j = 0; j < 4; j++)
                    zp[j] = (unsigned)f2b(zv[2 * j]) | ((unsigned)f2b(zv[2 * j + 1]) << 16);
                *(uint32x4*)(ZBFg + o) = zp;          // plain store (phase C only)
                *(uint32x4*)&zL[row * 136 + col] = zp;
            }
            __syncthreads();

            // GRU: wave -> 256 h-cols (16 col-tiles); TH (aliases S12, now dead)
            {
                bf16x8 zf[4];
#pragma unroll
                for (int ks = 0; ks < 4; ks++)
                    zf[ks] = *(const bf16x8*)&zL[lr * 136 + ks * 32 + lk * 8];
                const u16* gipt = GIP + (size_t)t * 786432;
#pragma unroll 2
                for (int i = 0; i < 16; i++) {
                    const int col = (wid * 16 + i) * 16 + lr;
                    f32x4 aR = {0.f,0.f,0.f,0.f}, aU = {0.f,0.f,0.f,0.f}, aN = {0.f,0.f,0.f,0.f};
#pragma unroll
                    for (int ks = 0; ks < 4; ks++) {
                        const int ko = ks * 32 + lk * 8;
                        bf16x8 bR = *(const bf16x8*)(wihZT + (size_t)(       col) * 128 + ko);
                        bf16x8 bU = *(const bf16x8*)(wihZT + (size_t)(1024 + col) * 128 + ko);
                        bf16x8 bN = *(const bf16x8*)(wihZT + (size_t)(2048 + col) * 128 + ko);
                        aR = __builtin_amdgcn_mfma_f32_16x16x32_bf16(zf[ks], bR, aR, 0, 0, 0);
                        aU = __builtin_amdgcn_mfma_f32_16x16x32_bf16(zf[ks], bU, aU, 0, 0, 0);
                        aN = __builtin_amdgcn_mfma_f32_16x16x32_bf16(zf[ks], bN, aN, 0, 0, 0);
                    }
                    const float bihR = gbih[col],        bhR = gbhh[col];
                    const float bihU = gbih[1024 + col], bhU = gbhh[1024 + col];
                    const float bihN = gbih[2048 + col], bhN = gbhh[2048 + col];
#pragma unroll
                    for (int r = 0; r < 4; r++) {
                        const u16* gp = gipt + (size_t)(r0 + lk * 4 + r) * 3072;
                        const float gr = aR[r] + b2f(gp[col])        + bihR + bhR;
                        const float gu = aU[r] + b2f(gp[1024 + col]) + bihU + bhU;
                        float gn       = aN[r] + b2f(gp[2048 + col]) + bihN;
                        const float rr_ = 1.f / (1.f + __expf(-gr));
                        const float uu  = 1.f / (1.f + __expf(-gu));
                        gn += rr_ * bhN;
                        const float e2 = __expf(-2.f * fabsf(gn));
                        float th = (1.f - e2) / (1.f + e2);
                        th = (gn < 0.f) ? -th : th;
                        TH[(lk * 4 + r) * 1032 + col] = f2b((1.f - uu) * th);
                    }
                }
            }
            __syncthreads();
            // h store: coherent 16B chunks (write-through so next step's plain
            // read gets fresh IC data with no dirty/stale copies anywhere)
            {
                u16* HSn = HS + (size_t)(t + 1) * 262144;
#pragma unroll
                for (int i = 0; i < 8; i++) {
                    const int c = i * 256 + tid;
                    const int row = c >> 7, coff = (c & 127) * 8;
                    st_cv16(HSn + (size_t)(r0 + row) * 1024 + coff,
                            *(const uint32x4*)&TH[row * 1032 + coff]);
                }
            }
        }
        gbar(bar, ++nb);
    }
}

// ---------- loss ----------
__global__ __launch_bounds__(256)
void loss_per_t(const float* __restrict__ x,
                const float* __restrict__ xm,
                const float* __restrict__ zm, const float* __restrict__ zs,
                const float* __restrict__ pm, const float* __restrict__ ps,
                float* __restrict__ kldT, float* __restrict__ nllT) {
    const int t = blockIdx.x, bb = threadIdx.x;
    float kld = 0.f, nll = 0.f;
    const size_t ozb = ((size_t)t * 256 + bb) * 128;
    for (int zz = 0; zz < 128; zz++) {
        const float qs = zs[ozb + zz], qm = zm[ozb + zz];
        const float pmv = pm[ozb + zz], psv = ps[ozb + zz];
        const float d = qm - pmv;
        kld += logf(psv + EPSC) - logf(qs + EPSC)
             + (qs * qs + d * d) / (2.f * psv * psv + EPSC) - 0.5f;
    }
    const size_t oxb = ((size_t)t * 256 + bb) * 512;
    const size_t oxi = ((size_t)bb * 256 + t) * 512;
    for (int dd = 0; dd < 512; dd++) {
        const float xv = x[oxi + dd];
        float m = xm[oxb + dd];
        m = fminf(fmaxf(m, 1e-6f), 1.f - 1e-6f);
        nll -= xv * logf(m) + (1.f - xv) * log1pf(-m);
    }
    __shared__ float sk[256], sn[256];
    sk[bb] = kld; sn[bb] = nll;
    __syncthreads();
    for (int s = 128; s > 0; s >>= 1) {
        if (bb < s) { sk[bb] += sk[bb + s]; sn[bb] += sn[bb + s]; }
        __syncthreads();
    }
    if (bb == 0) { kldT[t] = sk[0] / 256.f; nllT[t] = sn[0] / 256.f; }
}

__global__ __launch_bounds__(256)
void loss_final(const float* __restrict__ kldT, const float* __restrict__ nllT,
                float* __restrict__ out) {
    const int tid = threadIdx.x;
    __shared__ float s[256];
    s[tid] = kldT[tid] + nllT[tid];
    __syncthreads();
    for (int st = 128; st > 0; st >>= 1) {
        if (tid < st) s[tid] += s[tid + st];
        __syncthreads();
    }
    if (tid == 0) { out[0] = s[0]; out[1] = kldT[255]; out[2] = nllT[255]; }
}

extern "C" void kernel_launch(void* const* d_in, const int* in_sizes, int n_in,
                              void* d_out, int out_size, void* d_ws, size_t ws_size,
                              hipStream_t stream) {
    const float* x      = (const float*)d_in[0];
    const float* eps    = (const float*)d_in[1];
    const float* h0     = (const float*)d_in[2];
    const float* phix_w = (const float*)d_in[3];
    const float* phix_b = (const float*)d_in[4];
    const float* pm_w1  = (const float*)d_in[5];
    const float* pm_b1  = (const float*)d_in[6];
    const float* pm_w2  = (const float*)d_in[7];
    const float* pm_b2  = (const float*)d_in[8];
    const float* ps_w1  = (const float*)d_in[9];
    const float* ps_b1  = (const float*)d_in[10];
    const float* ps_w2  = (const float*)d_in[11];
    const float* ps_b2  = (const float*)d_in[12];
    const float* em_w1  = (const float*)d_in[13];
    const float* em_b1  = (const float*)d_in[14];
    const float* em_w2  = (const float*)d_in[15];
    const float* em_b2  = (const float*)d_in[16];
    const float* es_w1  = (const float*)d_in[17];
    const float* es_b1  = (const float*)d_in[18];
    const float* es_w2  = (const float*)d_in[19];
    const float* es_b2  = (const float*)d_in[20];
    const float* dm_w1  = (const float*)d_in[21];
    const float* dm_b1  = (const float*)d_in[22];
    const float* dm_w2  = (const float*)d_in[23];
    const float* dm_b2  = (const float*)d_in[24];
    const float* gwih   = (const float*)d_in[25];
    const float* gbih   = (const float*)d_in[26];
    const float* gbhh   = (const float*)d_in[27];
    float* out = (float*)d_out;

    if (ws_size < WS_NEED) return;
    char* w = (char*)d_ws;
    u16* phixWt  = (u16*)(w + oPHIXWT);
    u16* wcatT   = (u16*)(w + oWCATT);
    u16* emW2T   = (u16*)(w + oEMW2T);
    u16* esW2T   = (u16*)(w + oESW2T);
    u16* wihPhiT = (u16*)(w + oWIHPHIT);
    u16* wihZT   = (u16*)(w + oWIHZT);
    u16* pmW1T   = (u16*)(w + oPMW1T);
    u16* pmW2T   = (u16*)(w + oPMW2T);
    u16* psW1T   = (u16*)(w + oPSW1T);
    u16* psW2T   = (u16*)(w + oPSW2T);
    u16* dmW1T   = (u16*)(w + oDMW1T);
    u16* dmW2T   = (u16*)(w + oDMW2T);
    u16* HS      = (u16*)(w + oHS);
    u16* ZBF     = (u16*)(w + oZBF);
    u16* PHI     = (u16*)(w + oPHI);
    u16* GIP     = (u16*)(w + oGIP);
    u16* XbfT    = (u16*)(w + oGIP);                 // dead after phi GEMM
    float* PMbuf = (float*)(w + oGIP);               // phase C only (GIP dead)
    float* PSbuf = (float*)(w + oGIP + 33554432);
    unsigned* bar = (unsigned*)(w + oBAR);
    float* kldT  = (float*)(w + oKLDT);
    float* nllT  = (float*)(w + oNLLT);

    // ---- phase A ----
    conv_x4<<<32768, 256, 0, stream>>>(XbfT, x);
    conv_f32_bf16<<<1024, 256, 0, stream>>>(HS, h0, 262144);
    tr_conv<<<2048, 256, 0, stream>>>(phixWt, phix_w, 512, 1024, 1024);
    tr_conv<<<8192, 256, 0, stream>>>(wcatT, em_w1, 2048, 1024, 1024);
    tr_conv<<<8192, 256, 0, stream>>>(wcatT + (size_t)1024 * 2048, es_w1, 2048, 1024, 1024);
    tr_conv<<<512, 256, 0, stream>>>(emW2T, em_w2, 1024, 128, 128);
    tr_conv<<<512, 256, 0, stream>>>(esW2T, es_w2, 1024, 128, 128);
    tr_conv<<<12288, 256, 0, stream>>>(wihPhiT, gwih, 1024, 3072, 3072);
    tr_conv<<<1536, 256, 0, stream>>>(wihZT, gwih + (size_t)1024 * 3072, 128, 3072, 3072);
    tr_conv<<<4096, 256, 0, stream>>>(pmW1T, pm_w1, 1024, 1024, 1024);
    tr_conv<<<512, 256, 0, stream>>>(pmW2T, pm_w2, 1024, 128, 128);
    tr_conv<<<4096, 256, 0, stream>>>(psW1T, ps_w1, 1024, 1024, 1024);
    tr_conv<<<512, 256, 0, stream>>>(psW2T, ps_w2, 1024, 128, 128);
    tr_conv<<<4608, 256, 0, stream>>>(dmW1T, dm_w1, 1152, 1024, 1024);
    tr_conv<<<2048, 256, 0, stream>>>(dmW2T, dm_w2, 1024, 512, 512);

    gemm128<EPI_BF16_RELU><<<dim3(8, 512, 1), 256, 0, stream>>>(
        XbfT, nullptr, 512, 0, 512, phixWt, 512, phix_b, PHI, nullptr, 65536, 1024, 512, 512);
    gemm128<EPI_BF16_NONE><<<dim3(24, 512, 1), 256, 0, stream>>>(
        PHI, nullptr, 1024, 0, 1024, wihPhiT, 1024, nullptr, GIP, nullptr, 65536, 3072, 1024, 1024);

    // ---- phase B ----
    init_ctr<<<1, 256, 0, stream>>>(bar);
    vrnn_seq<<<256, 256, 0, stream>>>(eps, em_b1, es_b1, em_b2, es_b2, gbih, gbhh,
                                      (char*)d_ws, out);

    // ---- phase C ----
    gemm128<EPI_BF16_RELU><<<dim3(8, 512, 1), 256, 0, stream>>>(
        HS, nullptr, 1024, 0, 1024, pmW1T, 1024, pm_b1, PHI, nullptr, 65536, 1024, 1024, 1024);
    gemm128<EPI_F32_RELU><<<dim3(1, 512, 1), 256, 0, stream>>>(
        PHI, nullptr, 1024, 0, 1024, pmW2T, 1024, pm_b2, nullptr, PMbuf, 65536, 128, 1024, 1024);
    gemm128<EPI_BF16_RELU><<<dim3(8, 512, 1), 256, 0, stream>>>(
        HS, nullptr, 1024, 0, 1024, psW1T, 1024, ps_b1, PHI, nullptr, 65536, 1024, 1024, 1024);
    gemm128<EPI_F32_SP><<<dim3(1, 512, 1), 256, 0, stream>>>(
        PHI, nullptr, 1024, 0, 1024, psW2T, 1024, ps_b2, nullptr, PSbuf, 65536, 128, 1024, 1024);
    gemm128<EPI_BF16_RELU><<<dim3(8, 512, 1), 256, 0, stream>>>(
        HS, ZBF, 1024, 128, 1024, dmW1T, 1152, dm_b1, PHI, nullptr, 65536, 1024, 1152, 1152);
    gemm128<EPI_F32_SIG><<<dim3(4, 512, 1), 256, 0, stream>>>(
        PHI, nullptr, 1024, 0, 1024, dmW2T, 1024, dm_b2, nullptr, out + O_XM, 65536, 512, 1024, 1024);

    loss_per_t<<<256, 256, 0, stream>>>(x, out + O_XM, out + O_MU, out + O_STD,
                                        PMbuf, PSbuf, kldT, nllT);
    loss_final<<<1, 256, 0, stream>>>(kldT, nllT, out);
}

// Round 11
// 23492.058 us; speedup vs baseline: 1.0379x; 1.0379x over previous
//
#include <hip/hip_runtime.h>

typedef unsigned short u16;
typedef __bf16 bf16x8 __attribute__((ext_vector_type(8)));
typedef float f32x4 __attribute__((ext_vector_type(4)));
typedef unsigned uint32x4 __attribute__((ext_vector_type(4)));

#define EPSC 1e-6f

// ---------- helpers ----------
__device__ __forceinline__ float b2f(u16 x) { return __uint_as_float(((unsigned)x) << 16); }
__device__ __forceinline__ u16 f2b(float f) {
    unsigned u = __float_as_uint(f);
    unsigned r = (u + 0x7fffu + ((u >> 16) & 1u)) >> 16;
    return (u16)r;
}
__device__ __forceinline__ float softplusf(float x) {
    return fmaxf(x, 0.f) + log1pf(__expf(-fabsf(x)));
}

// coherent (cross-XCD) plain load/store: per-instruction sc0|sc1 policy.
// RULE: asm-load destinations must be statically indexed (VGPR-resident).
__device__ __forceinline__ void ld_cv16_issue(uint32x4& d, const void* p) {
    asm volatile("global_load_dwordx4 %0, %1, off sc0 sc1"
                 : "=v"(d) : "v"((unsigned long long)p) : "memory");
}
__device__ __forceinline__ unsigned ld_cv4(const void* p) {
    unsigned d;
    asm volatile("global_load_dword %0, %1, off sc0 sc1\n\ts_waitcnt vmcnt(0)"
                 : "=v"(d) : "v"((unsigned long long)p) : "memory");
    return d;
}
__device__ __forceinline__ void wait_vm0() {
    asm volatile("s_waitcnt vmcnt(0)" ::: "memory");
    __builtin_amdgcn_sched_barrier(0);
}
__device__ __forceinline__ void st_cv16(void* p, uint32x4 v) {
    asm volatile("global_store_dwordx4 %0, %1, off sc0 sc1"
                 :: "v"((unsigned long long)p), "v"(v) : "memory");
}
__device__ __forceinline__ void st_cv4(void* p, unsigned v) {
    asm volatile("global_store_dword %0, %1, off sc0 sc1"
                 :: "v"((unsigned long long)p), "v"(v) : "memory");
}

// ---------- conversion / transpose kernels ----------
__global__ void conv_x4(u16* __restrict__ dst, const float* __restrict__ x) {
    size_t i4 = (size_t)blockIdx.x * 256 + threadIdx.x;
    size_t o = i4 * 4;
    int d = (int)(o & 511);
    int b = (int)((o >> 9) & 255);
    int t = (int)(o >> 17);
    float4 v = *(const float4*)(x + ((size_t)b * 256 + t) * 512 + d);
    unsigned p0 = (unsigned)f2b(v.x) | ((unsigned)f2b(v.y) << 16);
    unsigned p1 = (unsigned)f2b(v.z) | ((unsigned)f2b(v.w) << 16);
    *(uint2*)(dst + o) = make_uint2(p0, p1);
}

__global__ void conv_f32_bf16(u16* __restrict__ dst, const float* __restrict__ src, int n) {
    int i = blockIdx.x * 256 + threadIdx.x;
    if (i < n) dst[i] = f2b(src[i]);
}

__global__ void tr_conv(u16* __restrict__ dst, const float* __restrict__ src,
                        int R, int C, int ld) {
    int idx = blockIdx.x * 256 + threadIdx.x;
    if (idx >= R * C) return;
    int c = idx / R, r = idx % R;
    dst[idx] = f2b(src[(size_t)r * ld + c]);
}

__global__ void init_ctr(unsigned* bar) {
#pragma unroll
    for (int i = 0; i < 4; i++) bar[threadIdx.x + i * 256] = 0u;
}

// ---------- generic 128x128 bf16 MFMA GEMM (phase A/C) ----------
enum { EPI_PARTIAL = 0, EPI_BF16_RELU = 1, EPI_BF16_NONE = 2,
       EPI_F32_RELU = 3, EPI_F32_SP = 4, EPI_F32_SIG = 5 };

template <int EPI>
__global__ __launch_bounds__(256)
void gemm128(const u16* __restrict__ A0, const u16* __restrict__ A1,
             int lda0, int lda1, int kSplit,
             const u16* __restrict__ Wt, int ldw,
             const float* __restrict__ bias,
             u16* __restrict__ Cb, float* __restrict__ Cf,
             int M, int N, int K, int kChunk) {
    __shared__ __align__(16) u16 As[128 * 72];
    __shared__ __align__(16) u16 Bs[128 * 72];
    const int tid = threadIdx.x;
    const int wid = tid >> 6, lane = tid & 63;
    const int wm = wid >> 1, wn = wid & 1;
    const int lr = lane & 15, lk = lane >> 4;
    const int m0 = blockIdx.y * 128, n0 = blockIdx.x * 128;
    const int kBeg = blockIdx.z * kChunk;
    const int rsub = lane >> 3;
    const int csub = (lane & 7) * 8;

    f32x4 acc[4][4];
#pragma unroll
    for (int i = 0; i < 4; i++)
#pragma unroll
        for (int j = 0; j < 4; j++) { f32x4 z = {0.f, 0.f, 0.f, 0.f}; acc[i][j] = z; }

    for (int kt = 0; kt < kChunk; kt += 64) {
        const int k0 = kBeg + kt;
        const u16* Ap; int kk, lda;
        if (k0 < kSplit) { Ap = A0; kk = k0; lda = lda0; }
        else             { Ap = A1; kk = k0 - kSplit; lda = lda1; }
        uint4 ra[4], rb[4];
#pragma unroll
        for (int i = 0; i < 4; i++) {
            const int q = wid * 4 + i;
            const int r = q * 8 + rsub;
            ra[i] = *(const uint4*)(Ap + (size_t)(m0 + r) * lda + kk + csub);
            rb[i] = *(const uint4*)(Wt + (size_t)(n0 + r) * ldw + k0 + csub);
        }
        __syncthreads();
#pragma unroll
        for (int i = 0; i < 4; i++) {
            const int q = wid * 4 + i;
            const int r = q * 8 + rsub;
            *(uint4*)&As[r * 72 + csub] = ra[i];
            *(uint4*)&Bs[r * 72 + csub] = rb[i];
        }
        __syncthreads();
#pragma unroll
        for (int s = 0; s < 2; s++) {
            bf16x8 af[4], bfr[4];
#pragma unroll
            for (int i = 0; i < 4; i++)
                af[i] = *(const bf16x8*)&As[(wm * 64 + i * 16 + lr) * 72 + s * 32 + lk * 8];
#pragma unroll
            for (int j = 0; j < 4; j++)
                bfr[j] = *(const bf16x8*)&Bs[(wn * 64 + j * 16 + lr) * 72 + s * 32 + lk * 8];
#pragma unroll
            for (int i = 0; i < 4; i++)
#pragma unroll
                for (int j = 0; j < 4; j++)
                    acc[i][j] = __builtin_amdgcn_mfma_f32_16x16x32_bf16(af[i], bfr[j], acc[i][j], 0, 0, 0);
        }
    }

    const int rowb = m0 + wm * 64, colb = n0 + wn * 64;
#pragma unroll
    for (int i = 0; i < 4; i++) {
#pragma unroll
        for (int j = 0; j < 4; j++) {
            const int col = colb + j * 16 + lr;
#pragma unroll
            for (int r = 0; r < 4; r++) {
                const int row = rowb + i * 16 + lk * 4 + r;
                float v = acc[i][j][r];
                if (EPI == EPI_PARTIAL) {
                    Cf[(size_t)blockIdx.z * ((size_t)M * N) + (size_t)row * N + col] = v;
                } else {
                    if (bias) v += bias[col];
                    if (EPI == EPI_BF16_RELU || EPI == EPI_F32_RELU) v = fmaxf(v, 0.f);
                    else if (EPI == EPI_F32_SP)  v = softplusf(v);
                    else if (EPI == EPI_F32_SIG) v = 1.f / (1.f + __expf(-v));
                    if (EPI == EPI_BF16_RELU || EPI == EPI_BF16_NONE) Cb[(size_t)row * N + col] = f2b(v);
                    else Cf[(size_t)row * N + col] = v;
                }
            }
        }
    }
}

// ---------- workspace layout (bytes) ----------
static constexpr size_t oPHIXWT  = 0;
static constexpr size_t oWCATT   = 1048576;
static constexpr size_t oEMW2T   = 9437184;
static constexpr size_t oESW2T   = 9699328;
static constexpr size_t oWIHPHIT = 9961472;
static constexpr size_t oWIHZT   = 16252928;
static constexpr size_t oPMW1T   = 17039360;
static constexpr size_t oPMW2T   = 19136512;
static constexpr size_t oPSW1T   = 19398656;
static constexpr size_t oPSW2T   = 21495808;
static constexpr size_t oDMW1T   = 21757952;
static constexpr size_t oDMW2T   = 24117248;
static constexpr size_t oHS      = 25165824;               // [T+1][B][H] bf16
static constexpr size_t oZBF     = 159907840;              // [T][B][Z] bf16
static constexpr size_t oT12     = 176685056;              // [256][2048] bf16
static constexpr size_t oBAR     = 177733632;              // slots[256] + hflags
static constexpr size_t oKLDT    = 177737728;
static constexpr size_t oNLLT    = 177738752;
static constexpr size_t oPHI     = 177739776;              // [65536][1024] bf16
static constexpr size_t oGIP     = 311957504;              // [65536][3072] bf16
static constexpr size_t WS_NEED  = 714610688;

static constexpr size_t NZ = (size_t)256 * 256 * 128;
static constexpr size_t O_Z  = 3;
static constexpr size_t O_MU = 3 + NZ;
static constexpr size_t O_STD = 3 + 2 * NZ;
static constexpr size_t O_XM = 3 + 3 * NZ;

// ---------- persistent sequential-phase kernel: 16 independent groups ----------
// Group g = bx>>4 owns batch rows 16g..16g+15; block n = bx&15 owns wcat
// column-slab n. No grid barrier: per-group flags only (sc1, IC-coherent,
// correct for any block->XCD mapping). W1 computes the phi K-half first
// (h-independent), then polls the group's h-flag, then the h K-half.
// A rotating worker (n == t&15) runs the fused z/GRU leg.
__global__ __launch_bounds__(256, 1)
void vrnn_seq(const float* __restrict__ eps,
              const float* __restrict__ em_b1, const float* __restrict__ es_b1,
              const float* __restrict__ em_b2, const float* __restrict__ es_b2,
              const float* __restrict__ gbih, const float* __restrict__ gbhh,
              char* ws, float* out) {
    __shared__ __align__(16) u16 SA[16 * 72];
    __shared__ __align__(16) u16 SB[128 * 72];
    __shared__ __align__(16) u16 TH16[16 * 136];
    __shared__ __align__(16) char POOL[16 * 2056 * 2];
    __shared__ float zmL[16 * 128], zsL[16 * 128];
    __shared__ __align__(16) u16 zL[16 * 136];

    const int bx = blockIdx.x, tid = threadIdx.x;
    const int wid = tid >> 6, lane = tid & 63;
    const int lr = lane & 15, lk = lane >> 4;

    const u16* wcatT = (const u16*)(ws + oWCATT);
    const u16* emW2T = (const u16*)(ws + oEMW2T);
    const u16* esW2T = (const u16*)(ws + oESW2T);
    const u16* wihZT = (const u16*)(ws + oWIHZT);
    const u16* PHI   = (const u16*)(ws + oPHI);
    const u16* GIP   = (const u16*)(ws + oGIP);
    u16* HS   = (u16*)(ws + oHS);
    u16* ZBFg = (u16*)(ws + oZBF);
    u16* T12g = (u16*)(ws + oT12);
    unsigned* bar = (unsigned*)(ws + oBAR);

    float* outZ  = out + O_Z;
    float* outMu = out + O_MU;
    float* outSd = out + O_STD;

    const int g = bx >> 4, n = bx & 15;
    const int r0 = g * 16;
    const u16* Bb = wcatT + (size_t)(n * 128) * 2048;
    unsigned* slot = bar + g * 16;          // 16 T12-ready slots for this group
    unsigned* hfl  = bar + 256 + g * 16;    // h-ready flag (64B-spread)

    const int a_row = tid >> 4, a_c8 = (tid & 15) * 8;
    const int a_half = (tid >> 3) & 1;
    const int a_lc = (tid & 7) * 8;
    const int brow = tid >> 1, bkc = (tid & 1) * 32;

    u16* S12 = (u16*)POOL;                  // [16][2056]
    u16* TH  = (u16*)POOL;                  // [16][1032] (S12 dead by then)

#define W1_HALF(AX, KOFF)                                                            \
    {                                                                                \
        uint32x4 rbr[2][4];                                                          \
        _Pragma("unroll")                                                            \
        for (int d = 0; d < 2; d++)                                                  \
            _Pragma("unroll")                                                        \
            for (int j = 0; j < 4; j++)                                              \
                rbr[d][j] = *(const uint32x4*)(Bb + (size_t)brow * 2048 + (KOFF) + d * 64 + bkc + j * 8); \
        _Pragma("unroll")                                                            \
        for (int kt = 0; kt < 16; kt++) {                                            \
            __syncthreads();                                                         \
            if (a_half == (kt & 1))                                                  \
                *(uint32x4*)&SA[a_row * 72 + a_lc] = AX[kt >> 1];                    \
            _Pragma("unroll")                                                        \
            for (int j = 0; j < 4; j++)                                              \
                *(uint32x4*)&SB[brow * 72 + bkc + j * 8] = rbr[kt & 1][j];           \
            __syncthreads();                                                         \
            if (kt + 2 < 16) {                                                       \
                _Pragma("unroll")                                                    \
                for (int j = 0; j < 4; j++)                                          \
                    rbr[kt & 1][j] = *(const uint32x4*)(Bb + (size_t)brow * 2048 + (KOFF) + (kt + 2) * 64 + bkc + j * 8); \
            }                                                                        \
            _Pragma("unroll")                                                        \
            for (int s = 0; s < 2; s++) {                                            \
                bf16x8 af = *(const bf16x8*)&SA[lr * 72 + s * 32 + lk * 8];          \
                bf16x8 b0 = *(const bf16x8*)&SB[(wid * 32 + lr) * 72 + s * 32 + lk * 8]; \
                bf16x8 b1 = *(const bf16x8*)&SB[(wid * 32 + 16 + lr) * 72 + s * 32 + lk * 8]; \
                acc0 = __builtin_amdgcn_mfma_f32_16x16x32_bf16(af, b0, acc0, 0, 0, 0); \
                acc1 = __builtin_amdgcn_mfma_f32_16x16x32_bf16(af, b1, acc1, 0, 0, 0); \
            }                                                                        \
        }                                                                            \
    }

#pragma unroll 1
    for (int t = 0; t < 256; t++) {
        const u16* PHIt = PHI + (size_t)t * 262144 + (size_t)r0 * 1024;
        const u16* HSt  = HS  + (size_t)t * 262144 + (size_t)r0 * 1024;
        f32x4 acc0 = {0.f,0.f,0.f,0.f}, acc1 = {0.f,0.f,0.f,0.f};

        // ---- phi K-half (1024..2047): no h dependence ----
        uint32x4 apx[8];
#pragma unroll
        for (int p = 0; p < 8; p++)
            apx[p] = *(const uint32x4*)(PHIt + (size_t)a_row * 1024 + a_c8 + p * 128);
        W1_HALF(apx, 1024)

        // ---- wait for h(t), then h K-half (0..1023) ----
        if (tid == 0) {
            while (ld_cv4(hfl) < (unsigned)t) __builtin_amdgcn_s_sleep(4);
        }
        __syncthreads();
        uint32x4 ahx[8];
#pragma unroll
        for (int p = 0; p < 8; p++)   // plain cached: h(t) addresses unique per t
            ahx[p] = *(const uint32x4*)(HSt + (size_t)a_row * 1024 + a_c8 + p * 128);
        W1_HALF(ahx, 0)

        // ---- epilogue: bias+relu -> LDS repack -> sc1 store + slot flag ----
        __syncthreads();
#pragma unroll
        for (int ct = 0; ct < 2; ct++) {
            const int colg = n * 128 + wid * 32 + ct * 16 + lr;
            const float bb = (colg < 1024) ? em_b1[colg] : es_b1[colg - 1024];
            const f32x4 a = ct ? acc1 : acc0;
#pragma unroll
            for (int r = 0; r < 4; r++)
                TH16[(lk * 4 + r) * 136 + wid * 32 + ct * 16 + lr] = f2b(fmaxf(a[r] + bb, 0.f));
        }
        __syncthreads();
        st_cv16(T12g + (size_t)(r0 + a_row) * 2048 + n * 128 + a_c8,
                *(const uint32x4*)&TH16[a_row * 136 + a_c8]);
        asm volatile("s_waitcnt vmcnt(0)" ::: "memory");
        __syncthreads();
        if (tid == 0) st_cv4(slot + n, (unsigned)(t + 1));

        // ---- rotating worker: fused zm/zs -> z -> GRU -> h(t+1) ----
        if (n == (t & 15)) {
            if (tid < 16) {
                while (ld_cv4(slot + tid) < (unsigned)(t + 1)) __builtin_amdgcn_s_sleep(4);
            }
            __syncthreads();
            // T12 rows -> LDS (sc1, 2 static batches)
            {
                uint32x4 s12r[16];
#pragma unroll
                for (int i = 0; i < 8; i++)
                    ld_cv16_issue(s12r[i], T12g + (size_t)(r0 + i) * 2048 + tid * 8);
                wait_vm0();
#pragma unroll
                for (int i = 8; i < 16; i++)
                    ld_cv16_issue(s12r[i], T12g + (size_t)(r0 + i) * 2048 + tid * 8);
#pragma unroll
                for (int i = 0; i < 8; i++)
                    *(uint32x4*)&S12[i * 2056 + tid * 8] = s12r[i];
                wait_vm0();
#pragma unroll
                for (int i = 8; i < 16; i++)
                    *(uint32x4*)&S12[i * 2056 + tid * 8] = s12r[i];
            }
            __syncthreads();

            // zm/zs
            {
                const int halfz = wid >> 1;
                const u16* Wz = halfz ? esW2T : emW2T;
                f32x4 az[4];
#pragma unroll
                for (int q = 0; q < 4; q++) { f32x4 z = {0.f,0.f,0.f,0.f}; az[q] = z; }
#pragma unroll 4
                for (int ks = 0; ks < 32; ks++) {
                    bf16x8 af = *(const bf16x8*)&S12[lr * 2056 + halfz * 1024 + ks * 32 + lk * 8];
#pragma unroll
                    for (int q = 0; q < 4; q++) {
                        const int c0 = (wid & 1) * 64 + q * 16;
                        bf16x8 bf = *(const bf16x8*)(Wz + (size_t)(c0 + lr) * 1024 + ks * 32 + lk * 8);
                        az[q] = __builtin_amdgcn_mfma_f32_16x16x32_bf16(af, bf, az[q], 0, 0, 0);
                    }
                }
#pragma unroll
                for (int q = 0; q < 4; q++) {
                    const int c = (wid & 1) * 64 + q * 16 + lr;
#pragma unroll
                    for (int r = 0; r < 4; r++) {
                        const int row = lk * 4 + r;
                        if (!halfz) zmL[row * 128 + c] = fmaxf(az[q][r] + em_b2[c], 0.f);
                        else        zsL[row * 128 + c] = softplusf(az[q][r] + es_b2[c]);
                    }
                }
            }
            __syncthreads();

            // z = zm + zs*eps; outputs (plain scalar stores; out+3 not 16B-aligned)
            {
                const int e = tid * 8, row = e >> 7, col = e & 127;
                const size_t o = (size_t)t * 32768 + (size_t)(r0 + row) * 128 + col;
                const float* ep = eps + o;
                float4 e0 = *(const float4*)ep, e1 = *(const float4*)(ep + 4);
                float zmv[8], zsv[8], zv[8];
#pragma unroll
                for (int i = 0; i < 8; i++) {
                    zmv[i] = zmL[row * 128 + col + i];
                    zsv[i] = zsL[row * 128 + col + i];
                    const float ev = (i < 4) ? (&e0.x)[i] : (&e1.x)[i - 4];
                    zv[i] = zmv[i] + zsv[i] * ev;
                }
#pragma unroll
                for (int i = 0; i < 8; i++) {
                    outMu[o + i] = zmv[i];
                    outSd[o + i] = zsv[i];
                    outZ[o + i]  = zv[i];
                }
                uint32x4 zp;
#pragma unroll
                for (int j = 0; j < 4; j++)
                    zp[j] = (unsigned)f2b(zv[2 * j]) | ((unsigned)f2b(zv[2 * j + 1]) << 16);
                *(uint32x4*)(ZBFg + o) = zp;
                *(uint32x4*)&zL[row * 136 + col] = zp;
            }
            __syncthreads();

            // GRU -> TH (aliases S12)
            {
                bf16x8 zf[4];
#pragma unroll
                for (int ks = 0; ks < 4; ks++)
                    zf[ks] = *(const bf16x8*)&zL[lr * 136 + ks * 32 + lk * 8];
                const u16* gipt = GIP + (size_t)t * 786432;
#pragma unroll 2
                for (int i = 0; i < 16; i++) {
                    const int col = (wid * 16 + i) * 16 + lr;
                    f32x4 aR = {0.f,0.f,0.f,0.f}, aU = {0.f,0.f,0.f,0.f}, aN = {0.f,0.f,0.f,0.f};
#pragma unroll
                    for (int ks = 0; ks < 4; ks++) {
                        const int ko = ks * 32 + lk * 8;
                        bf16x8 bR = *(const bf16x8*)(wihZT + (size_t)(       col) * 128 + ko);
                        bf16x8 bU = *(const bf16x8*)(wihZT + (size_t)(1024 + col) * 128 + ko);
                        bf16x8 bN = *(const bf16x8*)(wihZT + (size_t)(2048 + col) * 128 + ko);
                        aR = __builtin_amdgcn_mfma_f32_16x16x32_bf16(zf[ks], bR, aR, 0, 0, 0);
                        aU = __builtin_amdgcn_mfma_f32_16x16x32_bf16(zf[ks], bU, aU, 0, 0, 0);
                        aN = __builtin_amdgcn_mfma_f32_16x16x32_bf16(zf[ks], bN, aN, 0, 0, 0);
                    }
                    const float bihR = gbih[col],        bhR = gbhh[col];
                    const float bihU = gbih[1024 + col], bhU = gbhh[1024 + col];
                    const float bihN = gbih[2048 + col], bhN = gbhh[2048 + col];
#pragma unroll
                    for (int r = 0; r < 4; r++) {
                        const u16* gp = gipt + (size_t)(r0 + lk * 4 + r) * 3072;
                        const float gr = aR[r] + b2f(gp[col])        + bihR + bhR;
                        const float gu = aU[r] + b2f(gp[1024 + col]) + bihU + bhU;
                        float gn       = aN[r] + b2f(gp[2048 + col]) + bihN;
                        const float rr_ = 1.f / (1.f + __expf(-gr));
                        const float uu  = 1.f / (1.f + __expf(-gu));
                        gn += rr_ * bhN;
                        const float e2 = __expf(-2.f * fabsf(gn));
                        float th = (1.f - e2) / (1.f + e2);
                        th = (gn < 0.f) ? -th : th;
                        TH[(lk * 4 + r) * 1032 + col] = f2b((1.f - uu) * th);
                    }
                }
            }
            __syncthreads();
            // h(t+1) store (sc1) + h-flag
            {
                u16* HSn = HS + (size_t)(t + 1) * 262144;
#pragma unroll
                for (int i = 0; i < 8; i++) {
                    const int c = i * 256 + tid;
                    const int row = c >> 7, coff = (c & 127) * 8;
                    st_cv16(HSn + (size_t)(r0 + row) * 1024 + coff,
                            *(const uint32x4*)&TH[row * 1032 + coff]);
                }
            }
            asm volatile("s_waitcnt vmcnt(0)" ::: "memory");
            __syncthreads();
            if (tid == 0) st_cv4(hfl, (unsigned)(t + 1));
        }
    }
#undef W1_HALF
}

// ---------- loss ----------
__global__ __launch_bounds__(256)
void loss_per_t(const float* __restrict__ x,
                const float* __restrict__ xm,
                const float* __restrict__ zm, const float* __restrict__ zs,
                const float* __restrict__ pm, const float* __restrict__ ps,
                float* __restrict__ kldT, float* __restrict__ nllT) {
    const int t = blockIdx.x, bb = threadIdx.x;
    float kld = 0.f, nll = 0.f;
    const size_t ozb = ((size_t)t * 256 + bb) * 128;
    for (int zz = 0; zz < 128; zz++) {
        const float qs = zs[ozb + zz], qm = zm[ozb + zz];
        const float pmv = pm[ozb + zz], psv = ps[ozb + zz];
        const float d = qm - pmv;
        kld += logf(psv + EPSC) - logf(qs + EPSC)
             + (qs * qs + d * d) / (2.f * psv * psv + EPSC) - 0.5f;
    }
    const size_t oxb = ((size_t)t * 256 + bb) * 512;
    const size_t oxi = ((size_t)bb * 256 + t) * 512;
    for (int dd = 0; dd < 512; dd++) {
        const float xv = x[oxi + dd];
        float m = xm[oxb + dd];
        m = fminf(fmaxf(m, 1e-6f), 1.f - 1e-6f);
        nll -= xv * logf(m) + (1.f - xv) * log1pf(-m);
    }
    __shared__ float sk[256], sn[256];
    sk[bb] = kld; sn[bb] = nll;
    __syncthreads();
    for (int s = 128; s > 0; s >>= 1) {
        if (bb < s) { sk[bb] += sk[bb + s]; sn[bb] += sn[bb + s]; }
        __syncthreads();
    }
    if (bb == 0) { kldT[t] = sk[0] / 256.f; nllT[t] = sn[0] / 256.f; }
}

__global__ __launch_bounds__(256)
void loss_final(const float* __restrict__ kldT, const float* __restrict__ nllT,
                float* __restrict__ out) {
    const int tid = threadIdx.x;
    __shared__ float s[256];
    s[tid] = kldT[tid] + nllT[tid];
    __syncthreads();
    for (int st = 128; st > 0; st >>= 1) {
        if (tid < st) s[tid] += s[tid + st];
        __syncthreads();
    }
    if (tid == 0) { out[0] = s[0]; out[1] = kldT[255]; out[2] = nllT[255]; }
}

extern "C" void kernel_launch(void* const* d_in, const int* in_sizes, int n_in,
                              void* d_out, int out_size, void* d_ws, size_t ws_size,
                              hipStream_t stream) {
    const float* x      = (const float*)d_in[0];
    const float* eps    = (const float*)d_in[1];
    const float* h0     = (const float*)d_in[2];
    const float* phix_w = (const float*)d_in[3];
    const float* phix_b = (const float*)d_in[4];
    const float* pm_w1  = (const float*)d_in[5];
    const float* pm_b1  = (const float*)d_in[6];
    const float* pm_w2  = (const float*)d_in[7];
    const float* pm_b2  = (const float*)d_in[8];
    const float* ps_w1  = (const float*)d_in[9];
    const float* ps_b1  = (const float*)d_in[10];
    const float* ps_w2  = (const float*)d_in[11];
    const float* ps_b2  = (const float*)d_in[12];
    const float* em_w1  = (const float*)d_in[13];
    const float* em_b1  = (const float*)d_in[14];
    const float* em_w2  = (const float*)d_in[15];
    const float* em_b2  = (const float*)d_in[16];
    const float* es_w1  = (const float*)d_in[17];
    const float* es_b1  = (const float*)d_in[18];
    const float* es_w2  = (const float*)d_in[19];
    const float* es_b2  = (const float*)d_in[20];
    const float* dm_w1  = (const float*)d_in[21];
    const float* dm_b1  = (const float*)d_in[22];
    const float* dm_w2  = (const float*)d_in[23];
    const float* dm_b2  = (const float*)d_in[24];
    const float* gwih   = (const float*)d_in[25];
    const float* gbih   = (const float*)d_in[26];
    const float* gbhh   = (const float*)d_in[27];
    float* out = (float*)d_out;

    if (ws_size < WS_NEED) return;
    char* w = (char*)d_ws;
    u16* phixWt  = (u16*)(w + oPHIXWT);
    u16* wcatT   = (u16*)(w + oWCATT);
    u16* emW2T   = (u16*)(w + oEMW2T);
    u16* esW2T   = (u16*)(w + oESW2T);
    u16* wihPhiT = (u16*)(w + oWIHPHIT);
    u16* wihZT   = (u16*)(w + oWIHZT);
    u16* pmW1T   = (u16*)(w + oPMW1T);
    u16* pmW2T   = (u16*)(w + oPMW2T);
    u16* psW1T   = (u16*)(w + oPSW1T);
    u16* psW2T   = (u16*)(w + oPSW2T);
    u16* dmW1T   = (u16*)(w + oDMW1T);
    u16* dmW2T   = (u16*)(w + oDMW2T);
    u16* HS      = (u16*)(w + oHS);
    u16* ZBF     = (u16*)(w + oZBF);
    u16* PHI     = (u16*)(w + oPHI);
    u16* GIP     = (u16*)(w + oGIP);
    u16* XbfT    = (u16*)(w + oGIP);                 // dead after phi GEMM
    float* PMbuf = (float*)(w + oGIP);               // phase C only (GIP dead)
    float* PSbuf = (float*)(w + oGIP + 33554432);
    unsigned* bar = (unsigned*)(w + oBAR);
    float* kldT  = (float*)(w + oKLDT);
    float* nllT  = (float*)(w + oNLLT);

    // ---- phase A ----
    conv_x4<<<32768, 256, 0, stream>>>(XbfT, x);
    conv_f32_bf16<<<1024, 256, 0, stream>>>(HS, h0, 262144);
    tr_conv<<<2048, 256, 0, stream>>>(phixWt, phix_w, 512, 1024, 1024);
    tr_conv<<<8192, 256, 0, stream>>>(wcatT, em_w1, 2048, 1024, 1024);
    tr_conv<<<8192, 256, 0, stream>>>(wcatT + (size_t)1024 * 2048, es_w1, 2048, 1024, 1024);
    tr_conv<<<512, 256, 0, stream>>>(emW2T, em_w2, 1024, 128, 128);
    tr_conv<<<512, 256, 0, stream>>>(esW2T, es_w2, 1024, 128, 128);
    tr_conv<<<12288, 256, 0, stream>>>(wihPhiT, gwih, 1024, 3072, 3072);
    tr_conv<<<1536, 256, 0, stream>>>(wihZT, gwih + (size_t)1024 * 3072, 128, 3072, 3072);
    tr_conv<<<4096, 256, 0, stream>>>(pmW1T, pm_w1, 1024, 1024, 1024);
    tr_conv<<<512, 256, 0, stream>>>(pmW2T, pm_w2, 1024, 128, 128);
    tr_conv<<<4096, 256, 0, stream>>>(psW1T, ps_w1, 1024, 1024, 1024);
    tr_conv<<<512, 256, 0, stream>>>(psW2T, ps_w2, 1024, 128, 128);
    tr_conv<<<4608, 256, 0, stream>>>(dmW1T, dm_w1, 1152, 1024, 1024);
    tr_conv<<<2048, 256, 0, stream>>>(dmW2T, dm_w2, 1024, 512, 512);

    gemm128<EPI_BF16_RELU><<<dim3(8, 512, 1), 256, 0, stream>>>(
        XbfT, nullptr, 512, 0, 512, phixWt, 512, phix_b, PHI, nullptr, 65536, 1024, 512, 512);
    gemm128<EPI_BF16_NONE><<<dim3(24, 512, 1), 256, 0, stream>>>(
        PHI, nullptr, 1024, 0, 1024, wihPhiT, 1024, nullptr, GIP, nullptr, 65536, 3072, 1024, 1024);

    // ---- phase B ----
    init_ctr<<<1, 256, 0, stream>>>(bar);
    vrnn_seq<<<256, 256, 0, stream>>>(eps, em_b1, es_b1, em_b2, es_b2, gbih, gbhh,
                                      (char*)d_ws, out);

    // ---- phase C ----
    gemm128<EPI_BF16_RELU><<<dim3(8, 512, 1), 256, 0, stream>>>(
        HS, nullptr, 1024, 0, 1024, pmW1T, 1024, pm_b1, PHI, nullptr, 65536, 1024, 1024, 1024);
    gemm128<EPI_F32_RELU><<<dim3(1, 512, 1), 256, 0, stream>>>(
        PHI, nullptr, 1024, 0, 1024, pmW2T, 1024, pm_b2, nullptr, PMbuf, 65536, 128, 1024, 1024);
    gemm128<EPI_BF16_RELU><<<dim3(8, 512, 1), 256, 0, stream>>>(
        HS, nullptr, 1024, 0, 1024, psW1T, 1024, ps_b1, PHI, nullptr, 65536, 1024, 1024, 1024);
    gemm128<EPI_F32_SP><<<dim3(1, 512, 1), 256, 0, stream>>>(
        PHI, nullptr, 1024, 0, 1024, psW2T, 1024, ps_b2, nullptr, PSbuf, 65536, 128, 1024, 1024);
    gemm128<EPI_BF16_RELU><<<dim3(8, 512, 1), 256, 0, stream>>>(
        HS, ZBF, 1024, 128, 1024, dmW1T, 1152, dm_b1, PHI, nullptr, 65536, 1024, 1152, 1152);
    gemm128<EPI_F32_SIG><<<dim3(4, 512, 1), 256, 0, stream>>>(
        PHI, nullptr, 1024, 0, 1024, dmW2T, 1024, dm_b2, nullptr, out + O_XM, 65536, 512, 1024, 1024);

    loss_per_t<<<256, 256, 0, stream>>>(x, out + O_XM, out + O_MU, out + O_STD,
                                        PMbuf, PSbuf, kldT, nllT);
    loss_final<<<1, 256, 0, stream>>>(kldT, nllT, out);
}